// Round 2
// baseline (1878.587 us; speedup 1.0000x reference)
//
#include <hip/hip_runtime.h>
#include <hip/hip_bf16.h>
#include <math.h>
#include <stdint.h>

// ---------------- static config ----------------
#define LQ    2048   // sequence length (b=1)
#define DM    1024   // d_model
#define DIN   2048   // d_inner
#define NH    32     // heads
#define HD    64     // head dim p
#define DS    128    // d_state n
#define CONVD 2304   // DIN + 2*DS
#define DPROJ 4384   // 2*DIN + 2*DS + NH
#define NCH   16     // chunks
#define CQ    128    // chunk length
#define NVOC  32000

typedef __bf16 bf16_t;
typedef __attribute__((ext_vector_type(8))) __bf16 bf16x8;
typedef __attribute__((ext_vector_type(4))) float f32x4;

// ---- input dtype probe: norm_w is all ones.
// fp32 word0 = 0x3F800000 ; bf16 word0 = 0x3F803F80
__device__ __forceinline__ bool probe_f32(const uint32_t* p) {
    return p[0] == 0x3F800000u;
}
__device__ __forceinline__ float ld_in(const void* p, long i, bool f32) {
    return f32 ? ((const float*)p)[i] : (float)((const bf16_t*)p)[i];
}

// ---------------- weight convert: src(any dtype) -> bf16 ----------------
__global__ __launch_bounds__(256) void convert_kernel(
        const void* __restrict__ src, bf16_t* __restrict__ dst, long n,
        const uint32_t* __restrict__ probe) {
    bool f32 = probe_f32(probe);
    long i = ((long)blockIdx.x * 256 + threadIdx.x) * 8;
    if (i >= n) return;
    if (f32) {
        const float* s = (const float*)src + i;
        bf16x8 v;
        #pragma unroll
        for (int j = 0; j < 8; ++j) v[j] = (bf16_t)s[j];
        *(bf16x8*)&dst[i] = v;
    } else {
        *(bf16x8*)&dst[i] = *(const bf16x8*)((const bf16_t*)src + i);
    }
}

// ---------------- block reduce (256 threads) ----------------
__device__ __forceinline__ float block_reduce_sum_256(float v) {
    __shared__ float sb[4];
    #pragma unroll
    for (int off = 32; off > 0; off >>= 1) v += __shfl_down(v, off, 64);
    int lane = threadIdx.x & 63, w = threadIdx.x >> 6;
    if (lane == 0) sb[w] = v;
    __syncthreads();
    float s = sb[0] + sb[1] + sb[2] + sb[3];
    __syncthreads();
    return s;
}

// ---------------- embedding gather + unweighted rmsnorm (fp32 eps) ----------------
__global__ __launch_bounds__(256) void embed_norm_kernel(
        const int* __restrict__ idx, const void* __restrict__ emb,
        float* __restrict__ x, const uint32_t* __restrict__ probe) {
    bool f32 = probe_f32(probe);
    int t = blockIdx.x, tid = threadIdx.x;
    long base = (long)idx[t] * DM;
    float v[4], ss = 0.f;
    #pragma unroll
    for (int i = 0; i < 4; ++i) {
        v[i] = ld_in(emb, base + tid + i*256, f32);
        ss += v[i]*v[i];
    }
    ss = block_reduce_sum_256(ss);
    float rs = rsqrtf(ss / (float)DM + 1.1920929e-7f);
    float* xr = x + (size_t)t * DM;
    #pragma unroll
    for (int i = 0; i < 4; ++i) xr[tid + i*256] = v[i] * rs;
}

// ---------------- weighted rmsnorm fp32 -> bf16 (weight row base in elements) ----------
__global__ __launch_bounds__(256) void rmsnorm_kernel(
        const float* __restrict__ x, const void* __restrict__ w, long wbase,
        bf16_t* __restrict__ out, const uint32_t* __restrict__ probe) {
    bool f32 = probe_f32(probe);
    int t = blockIdx.x, tid = threadIdx.x;
    const float* xr = x + (size_t)t * DM;
    float v[4], ss = 0.f;
    #pragma unroll
    for (int i = 0; i < 4; ++i) { v[i] = xr[tid + i*256]; ss += v[i]*v[i]; }
    ss = block_reduce_sum_256(ss);
    float rs = rsqrtf(ss / (float)DM + 1e-5f);
    bf16_t* orow = out + (size_t)t * DM;
    #pragma unroll
    for (int i = 0; i < 4; ++i) {
        int j = tid + i*256;
        orow[j] = (bf16_t)(v[i] * rs * ld_in(w, wbase + j, f32));
    }
}

// ---------------- MFMA bf16 GEMM: C(M,N) = A(M,K) @ B(N,K)^T, fp32 out ----------------
template<int ADD>
__global__ __launch_bounds__(256) void gemm_bt(
        const bf16_t* __restrict__ A, const bf16_t* __restrict__ B,
        float* __restrict__ C, int M, int N, int K) {
    __shared__ bf16_t lA[128*64];
    __shared__ bf16_t lB[128*64];
    const int tid  = threadIdx.x;
    const int lane = tid & 63;
    const int lr   = lane & 15;
    const int quad = lane >> 4;
    const int wave = tid >> 6;
    const int m0 = blockIdx.y * 128;
    const int n0 = blockIdx.x * 128;
    const int wm = (wave >> 1) * 64;
    const int wn = (wave & 1) * 64;
    f32x4 acc[4][4] = {};
    for (int k0 = 0; k0 < K; k0 += 64) {
        __syncthreads();
        #pragma unroll
        for (int it = 0; it < 4; ++it) {
            int chunk = it*256 + tid;
            int row = chunk >> 3;
            int kc  = chunk & 7;
            int ar = m0 + row; if (ar >= M) ar = M - 1;
            int br = n0 + row; if (br >= N) br = N - 1;
            const bf16_t* ga = A + (size_t)ar * K + k0 + kc*8;
            const bf16_t* gb = B + (size_t)br * K + k0 + kc*8;
            __builtin_amdgcn_global_load_lds(
                (const __attribute__((address_space(1))) void*)ga,
                (__attribute__((address_space(3))) void*)(&lA[chunk*8]), 16, 0, 0);
            __builtin_amdgcn_global_load_lds(
                (const __attribute__((address_space(1))) void*)gb,
                (__attribute__((address_space(3))) void*)(&lB[chunk*8]), 16, 0, 0);
        }
        __syncthreads();
        #pragma unroll
        for (int kk = 0; kk < 64; kk += 32) {
            bf16x8 af[4], bfr[4];
            #pragma unroll
            for (int i = 0; i < 4; ++i)
                af[i] = *(const bf16x8*)&lA[(wm + i*16 + lr)*64 + kk + quad*8];
            #pragma unroll
            for (int i = 0; i < 4; ++i)
                bfr[i] = *(const bf16x8*)&lB[(wn + i*16 + lr)*64 + kk + quad*8];
            #pragma unroll
            for (int mi = 0; mi < 4; ++mi)
                #pragma unroll
                for (int ni = 0; ni < 4; ++ni)
                    acc[mi][ni] = __builtin_amdgcn_mfma_f32_16x16x32_bf16(
                        af[mi], bfr[ni], acc[mi][ni], 0, 0, 0);
        }
    }
    #pragma unroll
    for (int mi = 0; mi < 4; ++mi) {
        #pragma unroll
        for (int ni = 0; ni < 4; ++ni) {
            int col = n0 + wn + ni*16 + lr;
            if (col >= N) continue;
            #pragma unroll
            for (int r = 0; r < 4; ++r) {
                int row = m0 + wm + mi*16 + quad*4 + r;
                if (row < M) {
                    size_t off = (size_t)row * N + col;
                    if (ADD) C[off] += acc[mi][ni][r];
                    else     C[off]  = acc[mi][ni][r];
                }
            }
        }
    }
}

// ---------------- depthwise causal conv(4) + silu, plus dt/a precompute ----------------
__global__ __launch_bounds__(256) void conv_dt_kernel(
        const float* __restrict__ zx, const void* __restrict__ cw, long cwb,
        const void* __restrict__ cb, long cbb, const void* __restrict__ dtbias,
        const void* __restrict__ alog, long hb,
        float* __restrict__ xconv, float* __restrict__ dtb, float* __restrict__ ab,
        const uint32_t* __restrict__ probe) {
    bool f32 = probe_f32(probe);
    int t = blockIdx.x, tid = threadIdx.x;
    for (int ch = tid; ch < CONVD; ch += 256) {
        float acc = ld_in(cb, cbb + ch, f32);
        #pragma unroll
        for (int j = 0; j < 4; ++j) {
            int tt = t - 3 + j;
            if (tt >= 0) acc += zx[(size_t)tt*DPROJ + DIN + ch] * ld_in(cw, cwb + ch*4 + j, f32);
        }
        xconv[(size_t)t*CONVD + ch] = acc / (1.f + expf(-acc));   // silu
    }
    if (tid < NH) {
        float raw = zx[(size_t)t*DPROJ + DIN + CONVD + tid] + ld_in(dtbias, hb + tid, f32);
        float dt = raw > 20.f ? raw : log1pf(expf(raw));           // softplus
        dtb[(size_t)t*NH + tid] = dt;
        ab[(size_t)t*NH + tid] = -dt * expf(ld_in(alog, hb + tid, f32)); // dt * A
    }
}

// ---------------- per-chunk inclusive cumsum of a = dt*A ----------------
__global__ __launch_bounds__(128) void cumsum_kernel(
        const float* __restrict__ ab, float* __restrict__ LC) {
    int c = blockIdx.x, h = blockIdx.y, t = threadIdx.x;
    __shared__ float arr[128];
    arr[t] = ab[(size_t)(c*CQ + t)*NH + h];
    __syncthreads();
    for (int off = 1; off < 128; off <<= 1) {
        float v = arr[t];
        float add = (t >= off) ? arr[t - off] : 0.f;
        __syncthreads();
        arr[t] = v + add;
        __syncthreads();
    }
    LC[(size_t)(c*CQ + t)*NH + h] = arr[t];
}

// ---------------- chunk state: S[n][p] = sum_s exp(LClast-LC[s]) B_s[n] xdt_s[p] -------
__global__ __launch_bounds__(256) void chunkstate_kernel(
        const float* __restrict__ xconv, const float* __restrict__ dtb,
        const float* __restrict__ LC, float* __restrict__ S) {
    int c = blockIdx.x, h = blockIdx.y, tid = threadIdx.x;
    int n = tid & 127, ph = tid >> 7;
    __shared__ float Bsl[32*128];
    __shared__ float Xsl[32*64];
    __shared__ float wsl[32];
    const int c0 = c * CQ;
    float LClast = LC[(size_t)(c0 + CQ - 1)*NH + h];
    float acc[32];
    #pragma unroll
    for (int i = 0; i < 32; ++i) acc[i] = 0.f;
    for (int s0 = 0; s0 < CQ; s0 += 32) {
        __syncthreads();
        for (int e = tid; e < 32*128; e += 256) {
            int s = e >> 7, nn = e & 127;
            Bsl[e] = xconv[(size_t)(c0+s0+s)*CONVD + DIN + nn];
        }
        for (int e = tid; e < 32*64; e += 256) {
            int s = e >> 6, p = e & 63;
            int tt = c0 + s0 + s;
            Xsl[e] = xconv[(size_t)tt*CONVD + h*HD + p] * dtb[(size_t)tt*NH + h];
        }
        if (tid < 32) wsl[tid] = expf(LClast - LC[(size_t)(c0+s0+tid)*NH + h]);
        __syncthreads();
        for (int s = 0; s < 32; ++s) {
            float wb = wsl[s] * Bsl[s*128 + n];
            #pragma unroll
            for (int i = 0; i < 32; ++i)
                acc[i] += wb * Xsl[s*64 + ph*32 + i];
        }
    }
    float* Sp = S + ((size_t)(c*NH + h) << 13) + n*64 + ph*32;
    #pragma unroll
    for (int i = 0; i < 32; ++i) Sp[i] = acc[i];
}

// ---------------- inter-chunk recurrence ----------------
__global__ __launch_bounds__(256) void chunkrec_kernel(
        const float* __restrict__ S, const float* __restrict__ LC,
        float* __restrict__ Hin) {
    int h = blockIdx.x;
    int e = blockIdx.y*256 + threadIdx.x;
    float hv = 0.f;
    for (int c = 0; c < NCH; ++c) {
        size_t off = ((size_t)(c*NH + h) << 13) + e;
        Hin[off] = hv;
        float P = expf(LC[(size_t)(c*CQ + CQ - 1)*NH + h]);
        hv = P*hv + S[off];
    }
}

// ---------------- G[t][s] = C_t . B_s  (head-independent, per chunk) ----------------
__global__ __launch_bounds__(256) void gmat_kernel(
        const float* __restrict__ xconv, float* __restrict__ G) {
    int c = blockIdx.x, by = blockIdx.y, tid = threadIdx.x;
    int ti = tid & 127, q = tid >> 7;
    __shared__ float Csl[128*33];
    __shared__ float Bsl[32*33];
    const int c0 = c * CQ;
    float acc[16];
    #pragma unroll
    for (int i = 0; i < 16; ++i) acc[i] = 0.f;
    for (int n0 = 0; n0 < DS; n0 += 32) {
        __syncthreads();
        for (int e = tid; e < 128*32; e += 256) {
            int t = e >> 5, nn = e & 31;
            Csl[t*33+nn] = xconv[(size_t)(c0+t)*CONVD + DIN + DS + n0 + nn];
        }
        for (int e = tid; e < 32*32; e += 256) {
            int s = e >> 5, nn = e & 31;
            Bsl[s*33+nn] = xconv[(size_t)(c0 + by*32 + s)*CONVD + DIN + n0 + nn];
        }
        __syncthreads();
        for (int nn = 0; nn < 32; ++nn) {
            float cv = Csl[ti*33 + nn];
            #pragma unroll
            for (int s = 0; s < 16; ++s)
                acc[s] += cv * Bsl[(q*16 + s)*33 + nn];
        }
    }
    float* Gp = G + ((size_t)(c*CQ + ti))*CQ + by*32 + q*16;
    #pragma unroll
    for (int s = 0; s < 16; ++s) Gp[s] = acc[s];
}

// ---------------- chunk outputs ----------------
__global__ __launch_bounds__(256) void chunkout_kernel(
        const float* __restrict__ xconv, const float* __restrict__ dtb,
        const float* __restrict__ LC, const float* __restrict__ Hin,
        const float* __restrict__ G, const void* __restrict__ Dw, long hb,
        float* __restrict__ y, const uint32_t* __restrict__ probe) {
    bool f32 = probe_f32(probe);
    int c = blockIdx.x, h = blockIdx.y, tid = threadIdx.x;
    int ti = tid & 127, ph = tid >> 7;
    __shared__ float LCs[128];
    __shared__ float Asl[128*33];
    __shared__ float Bsl2[32*64];
    const int c0 = c * CQ;
    if (tid < 128) LCs[tid] = LC[(size_t)(c0 + tid)*NH + h];
    float facc[32];
    #pragma unroll
    for (int i = 0; i < 32; ++i) facc[i] = 0.f;
    for (int n0 = 0; n0 < DS; n0 += 32) {
        __syncthreads();
        for (int e = tid; e < 128*32; e += 256) {
            int t = e >> 5, nn = e & 31;
            Asl[t*33+nn] = xconv[(size_t)(c0+t)*CONVD + DIN + DS + n0 + nn];
        }
        for (int e = tid; e < 32*64; e += 256) {
            int nn = e >> 6, p = e & 63;
            Bsl2[e] = Hin[((size_t)(c*NH + h) << 13) + (n0+nn)*64 + p];
        }
        __syncthreads();
        for (int nn = 0; nn < 32; ++nn) {
            float cv = Asl[ti*33 + nn];
            #pragma unroll
            for (int i = 0; i < 32; ++i)
                facc[i] += cv * Bsl2[nn*64 + ph*32 + i];
        }
    }
    float et = expf(LCs[ti]);
    #pragma unroll
    for (int i = 0; i < 32; ++i) facc[i] *= et;
    for (int s0 = 0; s0 < CQ; s0 += 32) {
        __syncthreads();
        for (int e = tid; e < 128*32; e += 256) {
            int t = e >> 5, ss = e & 31;
            Asl[t*33+ss] = G[((size_t)(c*CQ + t))*CQ + s0 + ss];
        }
        for (int e = tid; e < 32*64; e += 256) {
            int ss = e >> 6, p = e & 63;
            int tt = c0 + s0 + ss;
            Bsl2[e] = xconv[(size_t)tt*CONVD + h*HD + p] * dtb[(size_t)tt*NH + h];
        }
        __syncthreads();
        for (int ss = 0; ss < 32; ++ss) {
            int sg = s0 + ss;
            float wdec = (sg <= ti) ? expf(LCs[ti] - LCs[sg]) : 0.f;
            float g = wdec * Asl[ti*33 + ss];
            #pragma unroll
            for (int i = 0; i < 32; ++i)
                facc[i] += g * Bsl2[ss*64 + ph*32 + i];
        }
    }
    float dcoef = ld_in(Dw, hb + h, f32);
    float* yp = y + (size_t)(c0 + ti)*DIN + h*HD + ph*32;
    const float* xp = xconv + (size_t)(c0 + ti)*CONVD + h*HD + ph*32;
    #pragma unroll
    for (int i = 0; i < 32; ++i) yp[i] = facc[i] + dcoef * xp[i];
}

// ---------------- gated RMS norm ----------------
__global__ __launch_bounds__(256) void gated_norm_kernel(
        const float* __restrict__ y, const float* __restrict__ zx,
        const void* __restrict__ gw, long gb, bf16_t* __restrict__ out,
        const uint32_t* __restrict__ probe) {
    bool f32 = probe_f32(probe);
    int t = blockIdx.x, tid = threadIdx.x;
    const float* yr = y + (size_t)t*DIN;
    const float* zr = zx + (size_t)t*DPROJ;
    float v[8], ss = 0.f;
    #pragma unroll
    for (int i = 0; i < 8; ++i) {
        int j = tid + i*256;
        float z = zr[j];
        float vv = yr[j] * (z / (1.f + expf(-z)));
        v[i] = vv; ss += vv*vv;
    }
    ss = block_reduce_sum_256(ss);
    float rs = rsqrtf(ss / (float)DIN + 1e-5f);
    bf16_t* orow = out + (size_t)t*DIN;
    #pragma unroll
    for (int i = 0; i < 8; ++i) {
        int j = tid + i*256;
        orow[j] = (bf16_t)(v[i] * rs * ld_in(gw, gb + j, f32));
    }
}

// ---------------- host launch ----------------
extern "C" void kernel_launch(void* const* d_in, const int* in_sizes, int n_in,
                              void* d_out, int out_size, void* d_ws, size_t ws_size,
                              hipStream_t stream) {
    const int*  idx        = (const int*)d_in[0];
    const void* emb        = d_in[1];
    const void* norm_w     = d_in[2];
    const void* in_proj_w  = d_in[3];
    const void* conv_w     = d_in[4];
    const void* conv_b     = d_in[5];
    const void* dt_bias    = d_in[6];
    const void* A_log      = d_in[7];
    const void* Dw         = d_in[8];
    const void* gnorm_w    = d_in[9];
    const void* out_proj_w = d_in[10];
    const void* normf_w    = d_in[11];
    const void* lm_head_w  = d_in[12];
    const uint32_t* probe  = (const uint32_t*)d_in[2];   // norm_w: all ones

    constexpr size_t SZ_X    = (size_t)LQ*DM*4;
    constexpr size_t SZ_XN   = (size_t)LQ*DM*2;
    constexpr size_t SZ_IN16 = (size_t)4*DPROJ*DM*2;
    constexpr size_t SZ_OUT16= (size_t)4*DM*DIN*2;
    constexpr size_t SZ_ZX   = (size_t)LQ*DPROJ*4;
    constexpr size_t SZ_XC   = (size_t)LQ*CONVD*4;
    constexpr size_t SZ_DT   = (size_t)LQ*NH*4;
    constexpr size_t SZ_S    = (size_t)NCH*NH*HD*DS*4;
    constexpr size_t SZ_G    = (size_t)NCH*CQ*CQ*4;
    char* ws = (char*)d_ws;
    size_t off = 0;
    float*  x     = (float*) (ws + off); off += SZ_X;
    bf16_t* xn16  = (bf16_t*)(ws + off); off += SZ_XN;
    bf16_t* in16  = (bf16_t*)(ws + off); off += SZ_IN16;
    bf16_t* out16 = (bf16_t*)(ws + off); off += SZ_OUT16;
    size_t pool0 = off;
    float*  zx    = (float*) (ws + off); off += SZ_ZX;
    float*  xconv = (float*) (ws + off); off += SZ_XC;
    float*  dtb   = (float*) (ws + off); off += SZ_DT;
    float*  ab    = (float*) (ws + off); off += SZ_DT;
    float*  LC    = (float*) (ws + off); off += SZ_DT;
    float*  S     = (float*) (ws + off); off += SZ_S;
    float*  Hin   = (float*) (ws + off); off += SZ_S;
    float*  G     = (float*) (ws + off); off += SZ_G;
    bf16_t* yb16  = (bf16_t*)xconv;        // overlays xconv (dead by gated_norm)
    bf16_t* lm16  = (bf16_t*)(ws + pool0); // overlays pool (free after layer loop)
    float*  ybuf  = S;                     // overlays S (dead after chunkrec)

    long n_in_w  = (long)4*DPROJ*DM;
    long n_out_w = (long)4*DM*DIN;
    convert_kernel<<<(n_in_w/8 + 255)/256, 256, 0, stream>>>(in_proj_w, in16, n_in_w, probe);
    convert_kernel<<<(n_out_w/8 + 255)/256, 256, 0, stream>>>(out_proj_w, out16, n_out_w, probe);

    embed_norm_kernel<<<LQ, 256, 0, stream>>>(idx, emb, x, probe);

    for (int l = 0; l < 4; ++l) {
        rmsnorm_kernel<<<LQ, 256, 0, stream>>>(x, norm_w, (long)l*DM, xn16, probe);
        gemm_bt<0><<<dim3(35, 16), 256, 0, stream>>>(
            xn16, in16 + (size_t)l*DPROJ*DM, zx, LQ, DPROJ, DM);
        conv_dt_kernel<<<LQ, 256, 0, stream>>>(
            zx, conv_w, (long)l*CONVD*4, conv_b, (long)l*CONVD,
            dt_bias, A_log, (long)l*NH, xconv, dtb, ab, probe);
        cumsum_kernel<<<dim3(NCH, NH), 128, 0, stream>>>(ab, LC);
        chunkstate_kernel<<<dim3(NCH, NH), 256, 0, stream>>>(xconv, dtb, LC, S);
        chunkrec_kernel<<<dim3(NH, 32), 256, 0, stream>>>(S, LC, Hin);
        gmat_kernel<<<dim3(NCH, 4), 256, 0, stream>>>(xconv, G);
        chunkout_kernel<<<dim3(NCH, NH), 256, 0, stream>>>(
            xconv, dtb, LC, Hin, G, Dw, (long)l*NH, ybuf, probe);
        gated_norm_kernel<<<LQ, 256, 0, stream>>>(ybuf, zx, gnorm_w, (long)l*DIN, yb16, probe);
        gemm_bt<1><<<dim3(8, 16), 256, 0, stream>>>(
            yb16, out16 + (size_t)l*DM*DIN, x, LQ, DM, DIN);
    }

    long n_lm = (long)NVOC*DM;
    convert_kernel<<<(n_lm/8 + 255)/256, 256, 0, stream>>>(lm_head_w, lm16, n_lm, probe);
    rmsnorm_kernel<<<LQ, 256, 0, stream>>>(x, normf_w, 0, xn16, probe);
    gemm_bt<0><<<dim3(NVOC/128, 16), 256, 0, stream>>>(xn16, lm16, (float*)d_out, LQ, NVOC, DM);
}